// Round 10
// baseline (62.759 us; speedup 1.0000x reference)
//
#include <hip/hip_runtime.h>
#include <hip/hip_bf16.h>

#define Bn 2048
#define Dn 512

typedef float f32x4 __attribute__((ext_vector_type(4)));
typedef int v8i __attribute__((ext_vector_type(8)));

union V8 { int4 q[2]; v8i v; };

typedef __attribute__((address_space(1))) const unsigned int gas_u32;
typedef __attribute__((address_space(3))) unsigned int las_u32;

__device__ __forceinline__ void gload16(const void* g, void* l) {
  __builtin_amdgcn_global_load_lds((gas_u32*)g, (las_u32*)l, 16, 0, 0);
}

// One block per row index: wave m normalizes row `blockIdx.x` of matrix m
// (0:O 1:H 2:P 3:N), writes fp8-e4m3 (O,H,P only) to nm8 in PLAIN row-major
// layout (MX MFMA wants 32 K-contiguous bytes per lane), keeps f32 in LDS,
// then computes the 6 pairwise diagonal dots. Zeroes rs.
__global__ __launch_bounds__(256) void normalize_kernel(
    const float* __restrict__ in0, const float* __restrict__ in1,
    const float* __restrict__ in2, const float* __restrict__ in3,
    unsigned char* __restrict__ nm8, float* __restrict__ rs, float* __restrict__ dd) {
  __shared__ float sv[4][Dn];
  __shared__ float red[4][6];
  int row = blockIdx.x;
  int wave = threadIdx.x >> 6, lane = threadIdx.x & 63;

  int g0 = blockIdx.x * 256 + threadIdx.x;
  if (g0 < 9 * Bn) rs[g0] = 0.0f;

  const float* src =
      (wave == 0 ? in0 : wave == 1 ? in1 : wave == 2 ? in2 : in3) + (size_t)row * Dn;
  int k = lane * 8;
  float4 x0 = *(const float4*)(src + k);
  float4 x1 = *(const float4*)(src + k + 4);
  float v[8] = {x0.x, x0.y, x0.z, x0.w, x1.x, x1.y, x1.z, x1.w};
  float ss = 0.f;
#pragma unroll
  for (int e = 0; e < 8; e++) ss = fmaf(v[e], v[e], ss);
#pragma unroll
  for (int off = 1; off < 64; off <<= 1) ss += __shfl_xor(ss, off, 64);
  float scale = 1.0f / fmaxf(sqrtf(ss), 1e-8f);
  float nv[8];
#pragma unroll
  for (int e = 0; e < 8; e++) {
    nv[e] = v[e] * scale;
    sv[wave][k + e] = nv[e];
  }
  if (wave < 3) {
    unsigned int lo = __builtin_amdgcn_cvt_pk_fp8_f32(nv[0], nv[1], 0u, false);
    lo = __builtin_amdgcn_cvt_pk_fp8_f32(nv[2], nv[3], lo, true);
    unsigned int hi = __builtin_amdgcn_cvt_pk_fp8_f32(nv[4], nv[5], 0u, false);
    hi = __builtin_amdgcn_cvt_pk_fp8_f32(nv[6], nv[7], hi, true);
    uint2 pk; pk.x = lo; pk.y = hi;
    *(uint2*)(nm8 + ((size_t)wave * Bn + row) * Dn + k) = pk;
  }
  __syncthreads();

  int t = threadIdx.x;
  float o0 = sv[0][2 * t], o1 = sv[0][2 * t + 1];
  float h0 = sv[1][2 * t], h1 = sv[1][2 * t + 1];
  float p0 = sv[2][2 * t], p1 = sv[2][2 * t + 1];
  float n0 = sv[3][2 * t], n1 = sv[3][2 * t + 1];
  float s[6];
  s[0] = fmaf(o0, h0, o1 * h1);
  s[1] = fmaf(o0, p0, o1 * p1);
  s[2] = fmaf(h0, p0, h1 * p1);
  s[3] = fmaf(o0, n0, o1 * n1);
  s[4] = fmaf(h0, n0, h1 * n1);
  s[5] = fmaf(p0, n0, p1 * n1);
#pragma unroll
  for (int off = 1; off < 64; off <<= 1) {
#pragma unroll
    for (int j = 0; j < 6; j++) s[j] += __shfl_xor(s[j], off, 64);
  }
  if (lane == 0) {
#pragma unroll
    for (int j = 0; j < 6; j++) red[wave][j] = s[j];
  }
  __syncthreads();
  if (threadIdx.x < 6) {
    int j = threadIdx.x;
    dd[j * Bn + row] = red[0][j] + red[1][j] + red[2][j] + red[3][j];
  }
}

// MX-scaled fp8 Gram kernel over M = [O;H;P] (6144x512 fp8, plain layout,
// 3 MB -> L2-resident). Upper-tri 128^2 tiles: 1176 blocks, XCD-chunked.
// 8 waves (2x4), each owns 64x32 output, full K.
//   A (shared by 4 column-waves): staged to LDS ONCE (64KB gload_lds,
//     both-sides 8-slot XOR swizzle u ^= row&7) -> zero barriers in K-loop.
//   B (wave-private): streamed global->reg; 3-slot ring, DISTANCE-2
//     prefetch (slot (t+2)%3 disjoint from t%3 -- R9's distance-3/3-slot
//     was a use-before-load hazard).
// Core: mfma_scale_f32_16x16x128_f8f6f4 with identity e8m0 scales (0x7F):
// K=512 in 4 steps, 32 MFMA/wave total (half of non-scaled), 2x peak rate.
#define GBM 128
#define NKT 4

__global__ __launch_bounds__(512) void gemm_fp8_kernel(const unsigned char* __restrict__ nm8,
                                                       float* __restrict__ rs) {
  __shared__ unsigned char As[65536];
  __shared__ float cb[2 * GBM];

  // XCD-chunked flat id -> upper-tri (by <= bx) over 48x48
  int id = ((int)blockIdx.x & 7) * 147 + ((int)blockIdx.x >> 3);
  int by = 0, rem = id, cnt = 48;
  while (rem >= cnt) { rem -= cnt; by++; cnt--; }
  int bx = by + rem;
  int u = by >> 4, v = bx >> 4;
  int rrow, rcol;
  if (u == v) { rrow = u; rcol = u; }
  else if (u == 0) { if (v == 1) { rrow = 3; rcol = 4; } else { rrow = 5; rcol = 6; } }
  else { rrow = 7; rcol = 8; }

  const unsigned char* gA = nm8 + ((size_t)u * Bn + (size_t)(by & 15) * GBM) * Dn;
  const unsigned char* gB = nm8 + ((size_t)v * Bn + (size_t)(bx & 15) * GBM) * Dn;

  int tid = threadIdx.x, lane = tid & 63, wave = tid >> 6;
  int wr = wave >> 2, wc = wave & 3;           // 2 x 4 wave grid: 64 x 32 each
  int c = lane & 15, rgrp = lane >> 4;
  int cx = c & 7;

  // ---- A stage: 8 rounds gload_lds; source pre-swizzled u ^= (row&7) ----
  {
    int usrc = (tid & 31) ^ ((tid >> 5) & 7);
    const unsigned char* sA = gA + (size_t)(tid >> 5) * Dn + usrc * 16;
    char* dA = (char*)As + (wave << 10);       // wave-uniform; HW adds lane*16
#pragma unroll
    for (int j = 0; j < 8; ++j) gload16(sA + j * 8192, dA + j * 8192);
  }

  // ---- B stream: lane covers rows (wc*32 + ni*16 + c), 32B at rgrp*32 ----
  const unsigned char* pb0 = gB + (size_t)(wc * 32 + c) * Dn + rgrp * 32;
  const unsigned char* pb1 = pb0 + (size_t)16 * Dn;
  V8 b[3][2];
#pragma unroll
  for (int t = 0; t < 2; ++t) {                // preload steps 0,1
    b[t][0].q[0] = *(const int4*)(pb0 + t * 128);
    b[t][0].q[1] = *(const int4*)(pb0 + t * 128 + 16);
    b[t][1].q[0] = *(const int4*)(pb1 + t * 128);
    b[t][1].q[1] = *(const int4*)(pb1 + t * 128 + 16);
  }

  __syncthreads();  // A staged (vmcnt drained), B slots 0,1 in regs

  int abase = (wr * 64 + c) * 512;
  f32x4 acc[4][2] = {};
#pragma unroll
  for (int t = 0; t < NKT; ++t) {
    int u0 = ((t * 8 + rgrp * 2) ^ cx) * 16;       // swizzled 16B units
    int u1 = ((t * 8 + rgrp * 2 + 1) ^ cx) * 16;
    V8 a[4];
#pragma unroll
    for (int mi = 0; mi < 4; ++mi) {
      a[mi].q[0] = *(const int4*)(As + abase + mi * 8192 + u0);
      a[mi].q[1] = *(const int4*)(As + abase + mi * 8192 + u1);
    }
    if (t + 2 < NKT) {                              // distance-2: slot disjoint from t%3
      int sl = (t + 2) % 3;
      b[sl][0].q[0] = *(const int4*)(pb0 + (t + 2) * 128);
      b[sl][0].q[1] = *(const int4*)(pb0 + (t + 2) * 128 + 16);
      b[sl][1].q[0] = *(const int4*)(pb1 + (t + 2) * 128);
      b[sl][1].q[1] = *(const int4*)(pb1 + (t + 2) * 128 + 16);
    }
    __builtin_amdgcn_s_setprio(1);
#pragma unroll
    for (int mi = 0; mi < 4; ++mi)
#pragma unroll
      for (int ni = 0; ni < 2; ++ni)
        acc[mi][ni] = __builtin_amdgcn_mfma_scale_f32_16x16x128_f8f6f4(
            a[mi].v, b[t % 3][ni].v, acc[mi][ni], 0, 0,
            0, 0x7F7F7F7F, 0, 0x7F7F7F7F);          // identity e8m0 scales
    __builtin_amdgcn_s_setprio(0);
  }

  // ---- epilogue: exp + block-level row/col combine in LDS, then atomics ----
  if (tid < 2 * GBM) cb[tid] = 0.0f;
  __syncthreads();
  float* crow = cb;
  float* ccol = cb + GBM;

  bool skip_diag = (by == bx);
#pragma unroll
  for (int mi = 0; mi < 4; ++mi)
#pragma unroll
    for (int ni = 0; ni < 2; ++ni)
#pragma unroll
      for (int r = 0; r < 4; ++r) {
        int lrow = wr * 64 + mi * 16 + rgrp * 4 + r;
        int lcol = wc * 32 + ni * 16 + c;
        float e = __expf(10.0f * acc[mi][ni][r] - 10.0f);
        acc[mi][ni][r] = (skip_diag && lrow == lcol) ? 0.0f : e;
      }

#pragma unroll
  for (int mi = 0; mi < 4; ++mi)
#pragma unroll
    for (int r = 0; r < 4; ++r) {
      float val = acc[mi][0][r] + acc[mi][1][r];
      val += __shfl_xor(val, 1, 64);
      val += __shfl_xor(val, 2, 64);
      val += __shfl_xor(val, 4, 64);
      val += __shfl_xor(val, 8, 64);
      if (c == 0) atomicAdd(&crow[wr * 64 + mi * 16 + rgrp * 4 + r], val);
    }
#pragma unroll
  for (int ni = 0; ni < 2; ++ni) {
    float cv = 0.f;
#pragma unroll
    for (int mi = 0; mi < 4; ++mi)
#pragma unroll
      for (int r = 0; r < 4; ++r) cv += acc[mi][ni][r];
    cv += __shfl_xor(cv, 16, 64);
    cv += __shfl_xor(cv, 32, 64);
    if (lane < 16) atomicAdd(&ccol[wc * 32 + ni * 16 + c], cv);
  }
  __syncthreads();

  float* rs_row = rs + rrow * Bn + (by & 15) * GBM;
  if (tid < GBM) {
    atomicAdd(rs_row + tid, crow[tid]);
  } else if (tid < 2 * GBM && by != bx) {
    // sym off-diag mirrors into same array (rcol==rrow); cross pairs -> transpose
    float* rs_col = rs + rcol * Bn + (bx & 15) * GBM;
    atomicAdd(rs_col + (tid - GBM), ccol[tid - GBM]);
  }
}

// rs layout: 0:OO 1:HH 2:PP 3:OH 4:HO 5:OP 6:PO 7:HP 8:PH
// dd layout: 0:oh 1:op 2:hp 3:on 4:hn 5:pn
__global__ __launch_bounds__(1024) void final_kernel(const float* __restrict__ rs,
                                                     const float* __restrict__ dd,
                                                     float* __restrict__ out) {
  int tid = threadIdx.x;  // 1024
  float l1 = 0.f, l2 = 0.f, l3 = 0.f;
  for (int i = tid; i < Bn; i += 1024) {
    float doh = dd[i], dop = dd[Bn + i], dhp = dd[2 * Bn + i];
    float ea = __expf(10.0f * dd[3 * Bn + i] - 10.0f);
    float eb = __expf(10.0f * dd[4 * Bn + i] - 10.0f);
    float ec = __expf(10.0f * dd[5 * Bn + i] - 10.0f);
    float r0 = rs[i], r1 = rs[Bn + i], r2 = rs[2 * Bn + i];
    float r3 = rs[3 * Bn + i], r4 = rs[4 * Bn + i], r5 = rs[5 * Bn + i];
    float r6 = rs[6 * Bn + i], r7 = rs[7 * Bn + i], r8 = rs[8 * Bn + i];
    l1 += 20.0f + logf(r0 + r3 + ea) + logf(r4 + r1 + ea) - 20.0f * doh;
    l2 += 20.0f + logf(r0 + r5 + ea) + logf(r6 + r2 + ea) - 20.0f * dop;
    l3 += 20.0f + logf(r1 + r7 + eb + ec) + logf(r8 + r2 + eb + ec) - 20.0f * dhp;
  }
  __shared__ float red[3][1024];
  red[0][tid] = l1; red[1][tid] = l2; red[2][tid] = l3;
  __syncthreads();
  for (int s = 512; s > 0; s >>= 1) {
    if (tid < s) {
      red[0][tid] += red[0][tid + s];
      red[1][tid] += red[1][tid + s];
      red[2][tid] += red[2][tid + s];
    }
    __syncthreads();
  }
  if (tid == 0) {
    out[0] = red[0][0] / 4096.0f;
    out[1] = red[1][0] / 4096.0f;
    out[2] = red[2][0] / 4096.0f;
  }
}

extern "C" void kernel_launch(void* const* d_in, const int* in_sizes, int n_in,
                              void* d_out, int out_size, void* d_ws, size_t ws_size,
                              hipStream_t stream) {
  const float* z0 = (const float*)d_in[0];
  const float* z1 = (const float*)d_in[1];
  const float* z2 = (const float*)d_in[2];
  const float* z3 = (const float*)d_in[3];
  float* out = (float*)d_out;

  unsigned char* nm8 = (unsigned char*)d_ws;                    // 3*2048*512 fp8 = 3 MB
  float* rs = (float*)((char*)d_ws + (size_t)3 * Bn * Dn);      // 9*2048 f32
  float* dd = rs + 9 * Bn;                                      // 6*2048 f32

  hipLaunchKernelGGL(normalize_kernel, dim3(2048), dim3(256), 0, stream,
                     z0, z1, z2, z3, nm8, rs, dd);
  hipLaunchKernelGGL(gemm_fp8_kernel, dim3(1176), dim3(512), 0, stream, nm8, rs);
  hipLaunchKernelGGL(final_kernel, dim3(1), dim3(1024), 0, stream, rs, dd, out);
}

// Round 11
// 52.580 us; speedup vs baseline: 1.1936x; 1.1936x over previous
//
#include <hip/hip_runtime.h>
#include <hip/hip_bf16.h>

#define Bn 2048
#define Dn 512

typedef float f32x4 __attribute__((ext_vector_type(4)));
typedef long long ll2 __attribute__((ext_vector_type(2)));

typedef __attribute__((address_space(1))) const unsigned int gas_u32;
typedef __attribute__((address_space(3))) unsigned int las_u32;

__device__ __forceinline__ void gload16(const void* g, void* l) {
  __builtin_amdgcn_global_load_lds((gas_u32*)g, (las_u32*)l, 16, 0, 0);
}

// One block per row index: wave m normalizes row `blockIdx.x` of matrix m
// (0:O 1:H 2:P 3:N), writes fp8-e4m3 (O,H,P only) to nm8 in K-PERMUTED
// layout (within each 64B k-block, 8B groups ordered [0,4,1,5,2,6,3,7] so
// one 16B read supplies both 8B MFMA k-slices of a K=64 window), keeps f32
// in LDS, then computes the 6 pairwise diagonal dots. Zeroes rs.
__global__ __launch_bounds__(256) void normalize_kernel(
    const float* __restrict__ in0, const float* __restrict__ in1,
    const float* __restrict__ in2, const float* __restrict__ in3,
    unsigned char* __restrict__ nm8, float* __restrict__ rs, float* __restrict__ dd) {
  __shared__ float sv[4][Dn];
  __shared__ float red[4][6];
  int row = blockIdx.x;
  int wave = threadIdx.x >> 6, lane = threadIdx.x & 63;

  int g0 = blockIdx.x * 256 + threadIdx.x;
  if (g0 < 9 * Bn) rs[g0] = 0.0f;

  const float* src =
      (wave == 0 ? in0 : wave == 1 ? in1 : wave == 2 ? in2 : in3) + (size_t)row * Dn;
  int k = lane * 8;
  float4 x0 = *(const float4*)(src + k);
  float4 x1 = *(const float4*)(src + k + 4);
  float v[8] = {x0.x, x0.y, x0.z, x0.w, x1.x, x1.y, x1.z, x1.w};
  float ss = 0.f;
#pragma unroll
  for (int e = 0; e < 8; e++) ss = fmaf(v[e], v[e], ss);
#pragma unroll
  for (int off = 1; off < 64; off <<= 1) ss += __shfl_xor(ss, off, 64);
  float scale = 1.0f / fmaxf(sqrtf(ss), 1e-8f);
  float nv[8];
#pragma unroll
  for (int e = 0; e < 8; e++) {
    nv[e] = v[e] * scale;
    sv[wave][k + e] = nv[e];
  }
  if (wave < 3) {
    unsigned int lo = __builtin_amdgcn_cvt_pk_fp8_f32(nv[0], nv[1], 0u, false);
    lo = __builtin_amdgcn_cvt_pk_fp8_f32(nv[2], nv[3], lo, true);
    unsigned int hi = __builtin_amdgcn_cvt_pk_fp8_f32(nv[4], nv[5], 0u, false);
    hi = __builtin_amdgcn_cvt_pk_fp8_f32(nv[6], nv[7], hi, true);
    uint2 pk; pk.x = lo; pk.y = hi;
    int kb = lane >> 3, g = lane & 7;
    int p = ((g & 3) << 1) | (g >> 2);
    *(uint2*)(nm8 + ((size_t)wave * Bn + row) * Dn + kb * 64 + p * 8) = pk;
  }
  __syncthreads();

  int t = threadIdx.x;
  float o0 = sv[0][2 * t], o1 = sv[0][2 * t + 1];
  float h0 = sv[1][2 * t], h1 = sv[1][2 * t + 1];
  float p0 = sv[2][2 * t], p1 = sv[2][2 * t + 1];
  float n0 = sv[3][2 * t], n1 = sv[3][2 * t + 1];
  float s[6];
  s[0] = fmaf(o0, h0, o1 * h1);
  s[1] = fmaf(o0, p0, o1 * p1);
  s[2] = fmaf(h0, p0, h1 * p1);
  s[3] = fmaf(o0, n0, o1 * n1);
  s[4] = fmaf(h0, n0, h1 * n1);
  s[5] = fmaf(p0, n0, p1 * n1);
#pragma unroll
  for (int off = 1; off < 64; off <<= 1) {
#pragma unroll
    for (int j = 0; j < 6; j++) s[j] += __shfl_xor(s[j], off, 64);
  }
  if (lane == 0) {
#pragma unroll
    for (int j = 0; j < 6; j++) red[wave][j] = s[j];
  }
  __syncthreads();
  if (threadIdx.x < 6) {
    int j = threadIdx.x;
    dd[j * Bn + row] = red[0][j] + red[1][j] + red[2][j] + red[3][j];
  }
}

// Pair-tiled hybrid fp8 Gram kernel over M = [O;H;P] (6144x512, K-permuted
// fp8, 3 MB -> L2-resident). Each block stages one 128-row A-panel to LDS
// ONCE (64KB, gload_lds, both-sides 16-slot XOR swizzle) then computes TWO
// adjacent upper-tri tiles (by,bx0) and (by,bx0+1), amortizing the staging
// prologue + pipeline ramp. 600 pair-blocks (Sum ceil((48-by)/2)), XCD
// chunking 600 = 8*75. 8 waves (2x4), each owns 64x32 per tile, full K.
// B wave-private global->reg, 3-slot ring, DISTANCE-2 prefetch (slot
// (t+2)%3 disjoint from t%3). Zero barriers inside the K-loop. Tile-2 B
// preloads issue before tile-1's epilogue (fly under it).
#define GBM 128
#define NKT 8

#define KLOOP(PB0, PB1)                                                      \
  _Pragma("unroll") for (int t = 0; t < NKT; ++t) {                          \
    int uoff = (((t * 4 + rgrp) ^ c) << 4);                                  \
    ll2 a[4];                                                                \
    _Pragma("unroll") for (int mi = 0; mi < 4; ++mi)                         \
        a[mi] = *(const ll2*)(As + abase + mi * 8192 + uoff);                \
    if (t + 2 < NKT) {                                                       \
      int sl = (t + 2) % 3;                                                  \
      b[sl][0] = *(const ll2*)((PB0) + (t + 2) * 64);                        \
      b[sl][1] = *(const ll2*)((PB1) + (t + 2) * 64);                        \
    }                                                                        \
    __builtin_amdgcn_s_setprio(1);                                           \
    _Pragma("unroll") for (int ks = 0; ks < 2; ++ks)                         \
        _Pragma("unroll") for (int mi = 0; mi < 4; ++mi)                     \
            _Pragma("unroll") for (int ni = 0; ni < 2; ++ni)                 \
                acc[mi][ni] = __builtin_amdgcn_mfma_f32_16x16x32_fp8_fp8(    \
                    a[mi][ks], b[t % 3][ni][ks], acc[mi][ni], 0, 0, 0);      \
    __builtin_amdgcn_s_setprio(0);                                           \
  }

#define EPILOGUE(BY, BX)                                                     \
  {                                                                          \
    __syncthreads();                                                         \
    if (tid < 2 * GBM) cb[tid] = 0.0f;                                       \
    __syncthreads();                                                         \
    bool skip_diag = ((BY) == (BX));                                         \
    _Pragma("unroll") for (int mi = 0; mi < 4; ++mi)                         \
        _Pragma("unroll") for (int ni = 0; ni < 2; ++ni)                     \
            _Pragma("unroll") for (int r = 0; r < 4; ++r) {                  \
      int lrow = wr * 64 + mi * 16 + rgrp * 4 + r;                           \
      int lcol = wc * 32 + ni * 16 + c;                                      \
      float e = __expf(10.0f * acc[mi][ni][r] - 10.0f);                      \
      acc[mi][ni][r] = (skip_diag && lrow == lcol) ? 0.0f : e;               \
    }                                                                        \
    _Pragma("unroll") for (int mi = 0; mi < 4; ++mi)                         \
        _Pragma("unroll") for (int r = 0; r < 4; ++r) {                      \
      float val = acc[mi][0][r] + acc[mi][1][r];                             \
      val += __shfl_xor(val, 1, 64);                                         \
      val += __shfl_xor(val, 2, 64);                                         \
      val += __shfl_xor(val, 4, 64);                                         \
      val += __shfl_xor(val, 8, 64);                                         \
      if (c == 0) atomicAdd(&cb[wr * 64 + mi * 16 + rgrp * 4 + r], val);     \
    }                                                                        \
    _Pragma("unroll") for (int ni = 0; ni < 2; ++ni) {                       \
      float cv = 0.f;                                                        \
      _Pragma("unroll") for (int mi = 0; mi < 4; ++mi)                       \
          _Pragma("unroll") for (int r = 0; r < 4; ++r) cv += acc[mi][ni][r];\
      cv += __shfl_xor(cv, 16, 64);                                          \
      cv += __shfl_xor(cv, 32, 64);                                          \
      if (lane < 16) atomicAdd(&cb[GBM + wc * 32 + ni * 16 + c], cv);        \
    }                                                                        \
    __syncthreads();                                                         \
    int u2 = (BY) >> 4, v2 = (BX) >> 4;                                      \
    int rrow, rcol;                                                          \
    if (u2 == v2) { rrow = u2; rcol = u2; }                                  \
    else if (u2 == 0) {                                                      \
      if (v2 == 1) { rrow = 3; rcol = 4; } else { rrow = 5; rcol = 6; }      \
    } else { rrow = 7; rcol = 8; }                                           \
    if (tid < GBM) {                                                         \
      atomicAdd(rs + rrow * Bn + ((BY) & 15) * GBM + tid, cb[tid]);          \
    } else if (tid < 2 * GBM && (BY) != (BX)) {                              \
      atomicAdd(rs + rcol * Bn + ((BX) & 15) * GBM + (tid - GBM),            \
                cb[tid]);                                                    \
    }                                                                        \
  }

__global__ __launch_bounds__(512, 4) void gemm_fp8_kernel(const unsigned char* __restrict__ nm8,
                                                          float* __restrict__ rs) {
  __shared__ unsigned char As[65536];
  __shared__ float cb[2 * GBM];

  // XCD-chunked pair id (600 = 8*75) -> (by, pair p)
  int id = ((int)blockIdx.x & 7) * 75 + ((int)blockIdx.x >> 3);
  int by = 0, rem = id;
  while (true) {
    int np = (49 - by) >> 1;  // ceil((48-by)/2) pairs in this row
    if (rem < np) break;
    rem -= np;
    ++by;
  }
  int bx0 = by + 2 * rem;
  bool has2 = (bx0 + 1 < 48);

  const unsigned char* gA =
      nm8 + ((size_t)(by >> 4) * Bn + (size_t)(by & 15) * GBM) * Dn;

  int tid = threadIdx.x, lane = tid & 63, wave = tid >> 6;
  int wr = wave >> 2, wc = wave & 3;  // 2 x 4 wave grid: 64 x 32 each
  int c = lane & 15, rgrp = lane >> 4;

  // ---- A stage: 8 rounds gload_lds; source pre-swizzled u ^= (row&15) ----
  {
    int usrc = (tid & 31) ^ ((tid >> 5) & 15);
    const unsigned char* sA = gA + (size_t)(tid >> 5) * Dn + usrc * 16;
    char* dA = (char*)As + (wave << 10);  // wave-uniform; HW adds lane*16
#pragma unroll
    for (int j = 0; j < 8; ++j) gload16(sA + j * 8192, dA + j * 8192);
  }

  // ---- tile-1 B preload: slots 0,1 ----
  const unsigned char* gB1 =
      nm8 + ((size_t)(bx0 >> 4) * Bn + (size_t)(bx0 & 15) * GBM) * Dn;
  const unsigned char* pb0 = gB1 + (size_t)(wc * 32 + c) * Dn + rgrp * 16;
  const unsigned char* pb1 = pb0 + (size_t)16 * Dn;
  ll2 b[3][2];
  b[0][0] = *(const ll2*)(pb0);
  b[0][1] = *(const ll2*)(pb1);
  b[1][0] = *(const ll2*)(pb0 + 64);
  b[1][1] = *(const ll2*)(pb1 + 64);

  __syncthreads();  // A staged (vmcnt drained), B slots 0,1 in regs

  int abase = (wr * 64 + c) * 512;
  f32x4 acc[4][2] = {};

  KLOOP(pb0, pb1)

  // issue tile-2's slot-0/1 preloads now: they fly under tile-1's epilogue
  int bx1 = bx0 + 1;
  const unsigned char* gB2 =
      nm8 + ((size_t)(bx1 >> 4) * Bn + (size_t)((bx1 & 15) & 15) * GBM) * Dn;
  const unsigned char* qb0 = gB2 + (size_t)(wc * 32 + c) * Dn + rgrp * 16;
  const unsigned char* qb1 = qb0 + (size_t)16 * Dn;
  if (has2) {
    b[0][0] = *(const ll2*)(qb0);
    b[0][1] = *(const ll2*)(qb1);
    b[1][0] = *(const ll2*)(qb0 + 64);
    b[1][1] = *(const ll2*)(qb1 + 64);
  }

  EPILOGUE(by, bx0)

  if (has2) {
#pragma unroll
    for (int mi = 0; mi < 4; ++mi)
#pragma unroll
      for (int ni = 0; ni < 2; ++ni) acc[mi][ni] = (f32x4){0.f, 0.f, 0.f, 0.f};

    KLOOP(qb0, qb1)
    EPILOGUE(by, bx1)
  }
}

// rs layout: 0:OO 1:HH 2:PP 3:OH 4:HO 5:OP 6:PO 7:HP 8:PH
// dd layout: 0:oh 1:op 2:hp 3:on 4:hn 5:pn
__global__ __launch_bounds__(1024) void final_kernel(const float* __restrict__ rs,
                                                     const float* __restrict__ dd,
                                                     float* __restrict__ out) {
  int tid = threadIdx.x;  // 1024
  float l1 = 0.f, l2 = 0.f, l3 = 0.f;
  for (int i = tid; i < Bn; i += 1024) {
    float doh = dd[i], dop = dd[Bn + i], dhp = dd[2 * Bn + i];
    float ea = __expf(10.0f * dd[3 * Bn + i] - 10.0f);
    float eb = __expf(10.0f * dd[4 * Bn + i] - 10.0f);
    float ec = __expf(10.0f * dd[5 * Bn + i] - 10.0f);
    float r0 = rs[i], r1 = rs[Bn + i], r2 = rs[2 * Bn + i];
    float r3 = rs[3 * Bn + i], r4 = rs[4 * Bn + i], r5 = rs[5 * Bn + i];
    float r6 = rs[6 * Bn + i], r7 = rs[7 * Bn + i], r8 = rs[8 * Bn + i];
    l1 += 20.0f + logf(r0 + r3 + ea) + logf(r4 + r1 + ea) - 20.0f * doh;
    l2 += 20.0f + logf(r0 + r5 + ea) + logf(r6 + r2 + ea) - 20.0f * dop;
    l3 += 20.0f + logf(r1 + r7 + eb + ec) + logf(r8 + r2 + eb + ec) - 20.0f * dhp;
  }
  __shared__ float red[3][1024];
  red[0][tid] = l1; red[1][tid] = l2; red[2][tid] = l3;
  __syncthreads();
  for (int s = 512; s > 0; s >>= 1) {
    if (tid < s) {
      red[0][tid] += red[0][tid + s];
      red[1][tid] += red[1][tid + s];
      red[2][tid] += red[2][tid + s];
    }
    __syncthreads();
  }
  if (tid == 0) {
    out[0] = red[0][0] / 4096.0f;
    out[1] = red[1][0] / 4096.0f;
    out[2] = red[2][0] / 4096.0f;
  }
}

extern "C" void kernel_launch(void* const* d_in, const int* in_sizes, int n_in,
                              void* d_out, int out_size, void* d_ws, size_t ws_size,
                              hipStream_t stream) {
  const float* z0 = (const float*)d_in[0];
  const float* z1 = (const float*)d_in[1];
  const float* z2 = (const float*)d_in[2];
  const float* z3 = (const float*)d_in[3];
  float* out = (float*)d_out;

  unsigned char* nm8 = (unsigned char*)d_ws;                    // 3*2048*512 fp8 = 3 MB
  float* rs = (float*)((char*)d_ws + (size_t)3 * Bn * Dn);      // 9*2048 f32
  float* dd = rs + 9 * Bn;                                      // 6*2048 f32

  hipLaunchKernelGGL(normalize_kernel, dim3(2048), dim3(256), 0, stream,
                     z0, z1, z2, z3, nm8, rs, dd);
  hipLaunchKernelGGL(gemm_fp8_kernel, dim3(600), dim3(512), 0, stream, nm8, rs);
  hipLaunchKernelGGL(final_kernel, dim3(1), dim3(1024), 0, stream, rs, dd, out);
}

// Round 12
// 39.924 us; speedup vs baseline: 1.5720x; 1.3170x over previous
//
#include <hip/hip_runtime.h>
#include <hip/hip_bf16.h>

#define Bn 2048
#define Dn 512

typedef float f32x4 __attribute__((ext_vector_type(4)));
typedef long long ll2 __attribute__((ext_vector_type(2)));

typedef __attribute__((address_space(1))) const unsigned int gas_u32;
typedef __attribute__((address_space(3))) unsigned int las_u32;

__device__ __forceinline__ void gload16(const void* g, void* l) {
  __builtin_amdgcn_global_load_lds((gas_u32*)g, (las_u32*)l, 16, 0, 0);
}

// One block per row index: wave m normalizes row `blockIdx.x` of matrix m
// (0:O 1:H 2:P 3:N), writes fp8-e4m3 (O,H,P only) to nm8 in K-PERMUTED
// layout (within each 64B k-block, 8B groups ordered [0,4,1,5,2,6,3,7] so
// one 16B read supplies both 8B MFMA k-slices of a K=64 window), keeps f32
// in LDS, then computes the 6 pairwise diagonal dots. Zeroes rs and out.
__global__ __launch_bounds__(256) void normalize_kernel(
    const float* __restrict__ in0, const float* __restrict__ in1,
    const float* __restrict__ in2, const float* __restrict__ in3,
    unsigned char* __restrict__ nm8, float* __restrict__ rs, float* __restrict__ dd,
    float* __restrict__ out) {
  __shared__ float sv[4][Dn];
  __shared__ float red[4][6];
  int row = blockIdx.x;
  int wave = threadIdx.x >> 6, lane = threadIdx.x & 63;

  int g0 = blockIdx.x * 256 + threadIdx.x;
  if (g0 < 9 * Bn) rs[g0] = 0.0f;
  if (g0 < 3) out[g0] = 0.0f;

  const float* src =
      (wave == 0 ? in0 : wave == 1 ? in1 : wave == 2 ? in2 : in3) + (size_t)row * Dn;
  int k = lane * 8;
  float4 x0 = *(const float4*)(src + k);
  float4 x1 = *(const float4*)(src + k + 4);
  float v[8] = {x0.x, x0.y, x0.z, x0.w, x1.x, x1.y, x1.z, x1.w};
  float ss = 0.f;
#pragma unroll
  for (int e = 0; e < 8; e++) ss = fmaf(v[e], v[e], ss);
#pragma unroll
  for (int off = 1; off < 64; off <<= 1) ss += __shfl_xor(ss, off, 64);
  float scale = 1.0f / fmaxf(sqrtf(ss), 1e-8f);
  float nv[8];
#pragma unroll
  for (int e = 0; e < 8; e++) {
    nv[e] = v[e] * scale;
    sv[wave][k + e] = nv[e];
  }
  if (wave < 3) {
    unsigned int lo = __builtin_amdgcn_cvt_pk_fp8_f32(nv[0], nv[1], 0u, false);
    lo = __builtin_amdgcn_cvt_pk_fp8_f32(nv[2], nv[3], lo, true);
    unsigned int hi = __builtin_amdgcn_cvt_pk_fp8_f32(nv[4], nv[5], 0u, false);
    hi = __builtin_amdgcn_cvt_pk_fp8_f32(nv[6], nv[7], hi, true);
    uint2 pk; pk.x = lo; pk.y = hi;
    int kb = lane >> 3, g = lane & 7;
    int p = ((g & 3) << 1) | (g >> 2);
    *(uint2*)(nm8 + ((size_t)wave * Bn + row) * Dn + kb * 64 + p * 8) = pk;
  }
  __syncthreads();

  int t = threadIdx.x;
  float o0 = sv[0][2 * t], o1 = sv[0][2 * t + 1];
  float h0 = sv[1][2 * t], h1 = sv[1][2 * t + 1];
  float p0 = sv[2][2 * t], p1 = sv[2][2 * t + 1];
  float n0 = sv[3][2 * t], n1 = sv[3][2 * t + 1];
  float s[6];
  s[0] = fmaf(o0, h0, o1 * h1);
  s[1] = fmaf(o0, p0, o1 * p1);
  s[2] = fmaf(h0, p0, h1 * p1);
  s[3] = fmaf(o0, n0, o1 * n1);
  s[4] = fmaf(h0, n0, h1 * n1);
  s[5] = fmaf(p0, n0, p1 * n1);
#pragma unroll
  for (int off = 1; off < 64; off <<= 1) {
#pragma unroll
    for (int j = 0; j < 6; j++) s[j] += __shfl_xor(s[j], off, 64);
  }
  if (lane == 0) {
#pragma unroll
    for (int j = 0; j < 6; j++) red[wave][j] = s[j];
  }
  __syncthreads();
  if (threadIdx.x < 6) {
    int j = threadIdx.x;
    dd[j * Bn + row] = red[0][j] + red[1][j] + red[2][j] + red[3][j];
  }
}

// Pipelined fp8 Gram kernel over M = [O;H;P] (6144x512, K-permuted fp8).
// Upper-tri 128^2 tiles: 1176 blocks, XCD-chunked (1176 = 8*147). 8 waves
// (2x4), each owns 64x32 output, full K. K = 8 tiles of 64B; 3-deep LDS
// ring (48KB -> 3 blocks/CU, 24 waves/CU), depth-2 prefetch, counted
// vmcnt(2)->0. Per phase: stage(t+2) | 6 ds_read_b128 | 16 MFMA (setprio)
// | vmcnt | s_barrier. Both-sides XOR swizzle on 16B units: source
// u ^= (row>>1)&3, read u = rgrp ^ ((c>>1)&3). b128 returns both k-slices
// (K-permuted layout). Verified conflict-free (R11: SQ_LDS_BANK_CONFLICT=0).
#define GBM 128
#define GBK 64
#define NKT 8
#define NBUF 3

__global__ __launch_bounds__(512, 6) void gemm_fp8_kernel(const unsigned char* __restrict__ nm8,
                                                          float* __restrict__ rs) {
  __shared__ unsigned char lds[NBUF * 16384];

  // XCD-chunked flat id -> upper-tri (by <= bx) over 48x48
  int id = ((int)blockIdx.x & 7) * 147 + ((int)blockIdx.x >> 3);
  int by = 0, rem = id, cnt = 48;
  while (rem >= cnt) { rem -= cnt; by++; cnt--; }
  int bx = by + rem;
  int u = by >> 4, v = bx >> 4;
  int rrow, rcol;
  if (u == v) { rrow = u; rcol = u; }
  else if (u == 0) { if (v == 1) { rrow = 3; rcol = 4; } else { rrow = 5; rcol = 6; } }
  else { rrow = 7; rcol = 8; }

  const unsigned char* gA = nm8 + ((size_t)u * Bn + (size_t)(by & 15) * GBM) * Dn;
  const unsigned char* gB = nm8 + ((size_t)v * Bn + (size_t)(bx & 15) * GBM) * Dn;

  int tid = threadIdx.x, lane = tid & 63, wave = tid >> 6;
  int wr = wave >> 2, wc = wave & 3;           // 2 x 4 wave grid: 64 x 32 each
  int c = lane & 15, rgrp = lane >> 4;
  int ru = ((rgrp ^ ((c >> 1) & 3)) << 4);     // read-side swizzled 16B unit

  // staging: thread covers LDS bytes [tid*16,+16) of the 8KB A (or B) panel
  int srow = tid >> 2;                          // 0..127
  int suu = (tid & 3) ^ ((srow >> 1) & 3);      // swizzled source 16B unit
  size_t aoff = (size_t)srow * Dn + suu * 16;
  const unsigned char* sA = gA + aoff;
  const unsigned char* sB = gB + aoff;
  int dbase = wave << 10;                       // wave-uniform dest; HW adds lane*16

#define STAGE(kt, j)                                         \
  {                                                          \
    unsigned char* d = lds + (j) * 16384;                    \
    gload16(sA + (kt) * GBK, d + dbase);                     \
    gload16(sB + (kt) * GBK, d + 8192 + dbase);              \
  }

  f32x4 acc[4][2] = {};

  // prologue: tiles 0,1 in flight (4 loads/wave)
  STAGE(0, 0);
  STAGE(1, 1);
  asm volatile("s_waitcnt vmcnt(2)" ::: "memory");  // tile 0 landed
  __builtin_amdgcn_s_barrier();
  asm volatile("" ::: "memory");

#pragma unroll
  for (int t = 0; t < NKT; ++t) {
    const unsigned char* As = lds + (t % 3) * 16384;
    const unsigned char* Bs = As + 8192;
    if (t + 2 < NKT) STAGE(t + 2, (t + 2) % 3);
    ll2 a[4];
    ll2 b[2];
#pragma unroll
    for (int mi = 0; mi < 4; ++mi)
      a[mi] = *(const ll2*)(As + (wr * 64 + mi * 16 + c) * 64 + ru);
#pragma unroll
    for (int ni = 0; ni < 2; ++ni)
      b[ni] = *(const ll2*)(Bs + (wc * 32 + ni * 16 + c) * 64 + ru);
    __builtin_amdgcn_s_setprio(1);
#pragma unroll
    for (int ks = 0; ks < 2; ++ks)
#pragma unroll
      for (int mi = 0; mi < 4; ++mi)
#pragma unroll
        for (int ni = 0; ni < 2; ++ni)
          acc[mi][ni] = __builtin_amdgcn_mfma_f32_16x16x32_fp8_fp8(
              a[mi][ks], b[ni][ks], acc[mi][ni], 0, 0, 0);
    __builtin_amdgcn_s_setprio(0);
    if (t + 2 < NKT) {
      asm volatile("s_waitcnt vmcnt(2)" ::: "memory");  // t+1 landed; t+2 in flight
    } else if (t + 1 < NKT) {
      asm volatile("s_waitcnt vmcnt(0)" ::: "memory");  // drain last tile
    }
    __builtin_amdgcn_s_barrier();
    asm volatile("" ::: "memory");
    __builtin_amdgcn_sched_barrier(0);
  }
#undef STAGE

  // ---- epilogue: exp + block-level row/col combine in LDS, then atomics ----
  float* crow = (float*)lds;          // [128] row partials (overlays ring)
  float* ccol = crow + GBM;           // [128] col partials
  __syncthreads();
  if (tid < 2 * GBM) ((float*)lds)[tid] = 0.0f;
  __syncthreads();

  bool skip_diag = (by == bx);
#pragma unroll
  for (int mi = 0; mi < 4; ++mi)
#pragma unroll
    for (int ni = 0; ni < 2; ++ni)
#pragma unroll
      for (int r = 0; r < 4; ++r) {
        int lrow = wr * 64 + mi * 16 + rgrp * 4 + r;
        int lcol = wc * 32 + ni * 16 + c;
        float e = __expf(10.0f * acc[mi][ni][r] - 10.0f);
        acc[mi][ni][r] = (skip_diag && lrow == lcol) ? 0.0f : e;
      }

#pragma unroll
  for (int mi = 0; mi < 4; ++mi)
#pragma unroll
    for (int r = 0; r < 4; ++r) {
      float val = acc[mi][0][r] + acc[mi][1][r];
      val += __shfl_xor(val, 1, 64);
      val += __shfl_xor(val, 2, 64);
      val += __shfl_xor(val, 4, 64);
      val += __shfl_xor(val, 8, 64);
      if (c == 0) atomicAdd(&crow[wr * 64 + mi * 16 + rgrp * 4 + r], val);
    }
#pragma unroll
  for (int ni = 0; ni < 2; ++ni) {
    float cv = 0.f;
#pragma unroll
    for (int mi = 0; mi < 4; ++mi)
#pragma unroll
      for (int r = 0; r < 4; ++r) cv += acc[mi][ni][r];
    cv += __shfl_xor(cv, 16, 64);
    cv += __shfl_xor(cv, 32, 64);
    if (lane < 16) atomicAdd(&ccol[wc * 32 + ni * 16 + c], cv);
  }
  __syncthreads();

  float* rs_row = rs + rrow * Bn + (by & 15) * GBM;
  if (tid < GBM) {
    atomicAdd(rs_row + tid, crow[tid]);
  } else if (tid < 2 * GBM && by != bx) {
    // sym off-diag mirrors into same array (rcol==rrow); cross pairs -> transpose
    float* rs_col = rs + rcol * Bn + (bx & 15) * GBM;
    atomicAdd(rs_col + (tid - GBM), ccol[tid - GBM]);
  }
}

// rs layout: 0:OO 1:HH 2:PP 3:OH 4:HO 5:OP 6:PO 7:HP 8:PH
// dd layout: 0:oh 1:op 2:hp 3:on 4:hn 5:pn
// 8 blocks x 256 threads, one row per thread; per-block LDS reduce then
// 3 atomicAdds into out (zeroed by normalize).
__global__ __launch_bounds__(256) void final_kernel(const float* __restrict__ rs,
                                                    const float* __restrict__ dd,
                                                    float* __restrict__ out) {
  int i = blockIdx.x * 256 + threadIdx.x;  // 0..2047
  float doh = dd[i], dop = dd[Bn + i], dhp = dd[2 * Bn + i];
  float ea = __expf(10.0f * dd[3 * Bn + i] - 10.0f);
  float eb = __expf(10.0f * dd[4 * Bn + i] - 10.0f);
  float ec = __expf(10.0f * dd[5 * Bn + i] - 10.0f);
  float r0 = rs[i], r1 = rs[Bn + i], r2 = rs[2 * Bn + i];
  float r3 = rs[3 * Bn + i], r4 = rs[4 * Bn + i], r5 = rs[5 * Bn + i];
  float r6 = rs[6 * Bn + i], r7 = rs[7 * Bn + i], r8 = rs[8 * Bn + i];
  float l1 = 20.0f + logf(r0 + r3 + ea) + logf(r4 + r1 + ea) - 20.0f * doh;
  float l2 = 20.0f + logf(r0 + r5 + ea) + logf(r6 + r2 + ea) - 20.0f * dop;
  float l3 = 20.0f + logf(r1 + r7 + eb + ec) + logf(r8 + r2 + eb + ec) - 20.0f * dhp;

  __shared__ float red[3][256];
  int tid = threadIdx.x;
  red[0][tid] = l1; red[1][tid] = l2; red[2][tid] = l3;
  __syncthreads();
  for (int s = 128; s > 0; s >>= 1) {
    if (tid < s) {
      red[0][tid] += red[0][tid + s];
      red[1][tid] += red[1][tid + s];
      red[2][tid] += red[2][tid + s];
    }
    __syncthreads();
  }
  if (tid < 3) atomicAdd(&out[tid], red[tid][0] * (1.0f / 4096.0f));
}

extern "C" void kernel_launch(void* const* d_in, const int* in_sizes, int n_in,
                              void* d_out, int out_size, void* d_ws, size_t ws_size,
                              hipStream_t stream) {
  const float* z0 = (const float*)d_in[0];
  const float* z1 = (const float*)d_in[1];
  const float* z2 = (const float*)d_in[2];
  const float* z3 = (const float*)d_in[3];
  float* out = (float*)d_out;

  unsigned char* nm8 = (unsigned char*)d_ws;                    // 3*2048*512 fp8 = 3 MB
  float* rs = (float*)((char*)d_ws + (size_t)3 * Bn * Dn);      // 9*2048 f32
  float* dd = rs + 9 * Bn;                                      // 6*2048 f32

  hipLaunchKernelGGL(normalize_kernel, dim3(2048), dim3(256), 0, stream,
                     z0, z1, z2, z3, nm8, rs, dd, out);
  hipLaunchKernelGGL(gemm_fp8_kernel, dim3(1176), dim3(512), 0, stream, nm8, rs);
  hipLaunchKernelGGL(final_kernel, dim3(8), dim3(256), 0, stream, rs, dd, out);
}